// Round 7
// baseline (313.298 us; speedup 1.0000x reference)
//
#include <hip/hip_runtime.h>

#define E_EDGES 327680
#define D 128

typedef __bf16 bf16x8 __attribute__((ext_vector_type(8)));
typedef float  f32x4  __attribute__((ext_vector_type(4)));
typedef float  f32x16 __attribute__((ext_vector_type(16)));

// ws layout (bytes). A-fragments of W^T for mfma_f32_32x32x16_bf16:
//   A[n][k]: lane l holds n = t*32 + (l&31), k = s*16 + 8*(l>>5) + j (j=0..7, k-pairs packed)
//   frag(layer,s,t) base: LxF + ((s*4+t)*64 + lane)*16
#define L1F 0        // 24 ksteps x 4 ntiles (K=384; g-part folded into bias)   96KB
#define L2F 98304    // 8 x 4                                                    32KB
#define L3F 131072
#define L4F 163840
#define BIASPF 196608  // 4 layers x 128 f32, rearranged [t][hi][reg]            2KB

__device__ __forceinline__ unsigned short f2bf(float f) {
  unsigned int u = __builtin_bit_cast(unsigned int, f);
  u += 0x7fffu + ((u >> 16) & 1u);   // RTNE
  return (unsigned short)(u >> 16);
}

__device__ __forceinline__ unsigned int cvtpk(float lo, float hi) {
  unsigned int r;
  asm("v_cvt_pk_bf16_f32 %0, %1, %2" : "=v"(r) : "v"(lo), "v"(hi));
  return r;
}

// v_permlane32_swap_b32 a, b: a.lanes[32:63] <-> b.lanes[0:31]
__device__ __forceinline__ void swap32(unsigned int& a, unsigned int& b) {
  asm("v_permlane32_swap_b32 %0, %1" : "+v"(a), "+v"(b));
}

__device__ __forceinline__ bf16x8 cvt8(f32x4 a, f32x4 b) {
  union { unsigned int u[4]; bf16x8 v; } r;
  r.u[0] = cvtpk(a[0], a[1]);
  r.u[1] = cvtpk(a[2], a[3]);
  r.u[2] = cvtpk(b[0], b[1]);
  r.u[3] = cvtpk(b[2], b[3]);
  return r.v;
}

// bias slot: n -> (t = n>>5, rem = n&31 = r + 4*hi + 8*q, reg = r + 4*q)
__device__ __forceinline__ int bias_slot(int n) {
  int t = n >> 5, rem = n & 31;
  int r = rem & 3, hi = (rem >> 2) & 1, q = rem >> 3;
  return t * 32 + hi * 16 + (r + 4 * q);
}

__global__ __launch_bounds__(256) void prep_weights(
    const float* __restrict__ W1, const float* __restrict__ W2,
    const float* __restrict__ W3, const float* __restrict__ W4,
    const float* __restrict__ b1, const float* __restrict__ b2,
    const float* __restrict__ b3, const float* __restrict__ b4,
    const float* __restrict__ glob, char* __restrict__ ws)
{
  float* biasP = (float*)(ws + BIASPF);
  if (blockIdx.x == 48) {
    int i = threadIdx.x;
    if (i < 128) {
      // layer-1 bias with g@W1[384:512] folded in
      float s = b1[i];
      for (int j = 0; j < 128; ++j) s += glob[j] * W1[(size_t)(384 + j) * D + i];
      biasP[0 * 128 + bias_slot(i)] = s;
    } else {
      int n = i - 128;
      biasP[1 * 128 + bias_slot(n)] = b2[n];
      biasP[2 * 128 + bias_slot(n)] = b3[n];
      biasP[3 * 128 + bias_slot(n)] = b4[n];
    }
    return;
  }
  int tid  = blockIdx.x * 256 + threadIdx.x;
  int lane = tid & 63;
  int f    = tid >> 6;            // 0..191
  const float* W; int base; int lf;
  if (f < 96)       { W = W1; base = L1F; lf = f; }
  else if (f < 128) { W = W2; base = L2F; lf = f - 96; }
  else if (f < 160) { W = W3; base = L3F; lf = f - 128; }
  else              { W = W4; base = L4F; lf = f - 160; }
  int s = lf >> 2, t = lf & 3;
  int k0 = s * 16 + (lane >> 5) * 8;
  int n  = t * 32 + (lane & 31);
  unsigned int pk[4];
#pragma unroll
  for (int p = 0; p < 4; ++p) {
    unsigned int lo = f2bf(W[(size_t)(k0 + 2 * p    ) * D + n]);
    unsigned int hi = f2bf(W[(size_t)(k0 + 2 * p + 1) * D + n]);
    pk[p] = lo | (hi << 16);
  }
  *(uint4*)(ws + base + (size_t)(lf * 64 + lane) * 16) =
      make_uint4(pk[0], pk[1], pk[2], pk[3]);
}

__global__ __launch_bounds__(256) void edge_mlp(
    const float* __restrict__ recv, const float* __restrict__ send,
    const float* __restrict__ edge, const char* __restrict__ ws,
    float* __restrict__ out)
{
  const int lane = threadIdx.x & 63;
  const int wid  = threadIdx.x >> 6;
  const int m    = lane & 31;          // edge-row within the wave's 32
  const int hi   = lane >> 5;
  const int row0 = blockIdx.x * 128 + wid * 32;
  const float* biasF = (const float*)(ws + BIASPF);

  f32x16 acc[4];
#pragma unroll
  for (int t = 0; t < 4; ++t) acc[t] = (f32x16)0.0f;

  bf16x8 bn[8];   // next-layer B fragments (h, register-resident)

  // epilogue: bias (+relu) on D' = W^T x^T, convert to next layer's B frags
  auto epilogue = [&](int layerOff, bool relu) {
#pragma unroll
    for (int t = 0; t < 4; ++t) {
      const float* bp = biasF + layerOff + t * 32 + hi * 16;
      f32x16 v = acc[t];
#pragma unroll
      for (int q = 0; q < 4; ++q) {
        f32x4 bq = *(const f32x4*)(bp + q * 4);
#pragma unroll
        for (int r = 0; r < 4; ++r) {
          float x = v[q * 4 + r] + bq[r];
          v[q * 4 + r] = relu ? fmaxf(x, 0.0f) : x;
        }
      }
      // regs 0..7 -> kstep 2t (k'=32t..32t+15); regs 8..15 -> kstep 2t+1
      {
        unsigned int u0 = cvtpk(v[0], v[1]), u1 = cvtpk(v[2], v[3]);
        unsigned int w0 = cvtpk(v[4], v[5]), w1 = cvtpk(v[6], v[7]);
        swap32(u0, w0); swap32(u1, w1);
        union { unsigned int u[4]; bf16x8 b; } pk;
        pk.u[0] = u0; pk.u[1] = u1; pk.u[2] = w0; pk.u[3] = w1;
        bn[2 * t] = pk.b;
      }
      {
        unsigned int u0 = cvtpk(v[8], v[9]),  u1 = cvtpk(v[10], v[11]);
        unsigned int w0 = cvtpk(v[12], v[13]), w1 = cvtpk(v[14], v[15]);
        swap32(u0, w0); swap32(u1, w1);
        union { unsigned int u[4]; bf16x8 b; } pk;
        pk.u[0] = u0; pk.u[1] = u1; pk.u[2] = w0; pk.u[3] = w1;
        bn[2 * t + 1] = pk.b;
      }
      acc[t] = (f32x16)0.0f;
    }
  };

  // -------- layer 1: K = 384 streamed from [recv|send|edge], B = x^T from global --------
  const float* rp0 = recv + (size_t)(row0 + m) * D + hi * 8;
  const float* rp1 = send + (size_t)(row0 + m) * D + hi * 8;
  const float* rp2 = edge + (size_t)(row0 + m) * D + hi * 8;
#pragma unroll
  for (int s = 0; s < 24; ++s) {
    const float* p = (s < 8 ? rp0 : s < 16 ? rp1 : rp2) + (s & 7) * 16;
    f32x4 v0 = *(const f32x4*)p;
    f32x4 v1 = *(const f32x4*)(p + 4);
    bf16x8 b = cvt8(v0, v1);
#pragma unroll
    for (int t = 0; t < 4; ++t) {
      bf16x8 a = *(const bf16x8*)(ws + L1F + (size_t)((s * 4 + t) * 64 + lane) * 16);
      acc[t] = __builtin_amdgcn_mfma_f32_32x32x16_bf16(a, b, acc[t], 0, 0, 0);
    }
  }
  epilogue(0, true);

  auto do_layer = [&](int fragOff) {
#pragma unroll
    for (int s = 0; s < 8; ++s) {
      bf16x8 b = bn[s];
#pragma unroll
      for (int t = 0; t < 4; ++t) {
        bf16x8 a = *(const bf16x8*)(ws + fragOff + (size_t)((s * 4 + t) * 64 + lane) * 16);
        acc[t] = __builtin_amdgcn_mfma_f32_32x32x16_bf16(a, b, acc[t], 0, 0, 0);
      }
    }
  };

  do_layer(L2F);
  epilogue(128, true);
  do_layer(L3F);
  epilogue(256, true);
  do_layer(L4F);

  // final: bias, no relu; n = 32t + 8q + 4hi + r is reg-consecutive -> dwordx4 stores
#pragma unroll
  for (int t = 0; t < 4; ++t) {
    const float* bp = biasF + 3 * 128 + t * 32 + hi * 16;
    float* po = out + (size_t)(row0 + m) * D + t * 32 + hi * 4;
#pragma unroll
    for (int q = 0; q < 4; ++q) {
      f32x4 bq = *(const f32x4*)(bp + q * 4);
      f32x4 sv;
#pragma unroll
      for (int r = 0; r < 4; ++r) sv[r] = acc[t][q * 4 + r] + bq[r];
      *(f32x4*)(po + q * 8) = sv;
    }
  }
}

extern "C" void kernel_launch(void* const* d_in, const int* in_sizes, int n_in,
                              void* d_out, int out_size, void* d_ws, size_t ws_size,
                              hipStream_t stream)
{
  const float* recv = (const float*)d_in[0];
  const float* send = (const float*)d_in[1];
  const float* edge = (const float*)d_in[2];
  const float* glob = (const float*)d_in[3];
  const float* W1 = (const float*)d_in[4];
  const float* b1 = (const float*)d_in[5];
  const float* W2 = (const float*)d_in[6];
  const float* b2 = (const float*)d_in[7];
  const float* W3 = (const float*)d_in[8];
  const float* b3 = (const float*)d_in[9];
  const float* W4 = (const float*)d_in[10];
  const float* b4 = (const float*)d_in[11];
  char* ws = (char*)d_ws;

  prep_weights<<<49, 256, 0, stream>>>(W1, W2, W3, W4, b1, b2, b3, b4, glob, ws);
  edge_mlp<<<E_EDGES / 128, 256, 0, stream>>>(recv, send, edge, ws, (float*)d_out);
}

// Round 8
// 248.206 us; speedup vs baseline: 1.2623x; 1.2623x over previous
//
#include <hip/hip_runtime.h>

#define E_EDGES 327680
#define D 128
#define TPB 512            // 8 waves; each wave owns 32 edge-rows
#define ROWS_PER_BLOCK 256

typedef __bf16 bf16x8 __attribute__((ext_vector_type(8)));
typedef float  f32x4  __attribute__((ext_vector_type(4)));
typedef float  f32x16 __attribute__((ext_vector_type(16)));

typedef bf16x8 __attribute__((may_alias)) bf16x8a;
typedef uint4  __attribute__((may_alias)) uint4a;

// ws layout (bytes). A-fragments of W^T for mfma_f32_32x32x16_bf16:
//   A[n][k]: lane l holds n = t*32 + (l&31), k = s*16 + 8*(l>>5) + j (j=0..7, k-pairs packed)
//   frag(layer,s,t) base: LxF + (s*4+t)*1024 + lane*16
#define L1F 0        // 24 ksteps x 4 ntiles (K=384; g-part folded into bias)   96KB
#define L2F 98304    // 8 x 4                                                    32KB
#define L3F 131072
#define L4F 163840
#define BIASPF 196608  // 4 layers x 128 f32, rearranged [t][hi][reg]            2KB

__device__ __forceinline__ unsigned short f2bf(float f) {
  unsigned int u = __builtin_bit_cast(unsigned int, f);
  u += 0x7fffu + ((u >> 16) & 1u);   // RTNE
  return (unsigned short)(u >> 16);
}

__device__ __forceinline__ unsigned int cvtpk(float lo, float hi) {
  unsigned int r;
  asm("v_cvt_pk_bf16_f32 %0, %1, %2" : "=v"(r) : "v"(lo), "v"(hi));
  return r;
}

// v_permlane32_swap_b32 a, b: a.lanes[32:63] <-> b.lanes[0:31]
__device__ __forceinline__ void swap32(unsigned int& a, unsigned int& b) {
  asm("v_permlane32_swap_b32 %0, %1" : "+v"(a), "+v"(b));
}

__device__ __forceinline__ bf16x8 cvt8(f32x4 a, f32x4 b) {
  union { unsigned int u[4]; bf16x8 v; } r;
  r.u[0] = cvtpk(a[0], a[1]);
  r.u[1] = cvtpk(a[2], a[3]);
  r.u[2] = cvtpk(b[0], b[1]);
  r.u[3] = cvtpk(b[2], b[3]);
  return r.v;
}

// bias slot: n -> (t = n>>5, rem = n&31 = r + 4*hi + 8*q, reg = r + 4*q)
__device__ __forceinline__ int bias_slot(int n) {
  int t = n >> 5, rem = n & 31;
  int r = rem & 3, hi = (rem >> 2) & 1, q = rem >> 3;
  return t * 32 + hi * 16 + (r + 4 * q);
}

__global__ __launch_bounds__(256) void prep_weights(
    const float* __restrict__ W1, const float* __restrict__ W2,
    const float* __restrict__ W3, const float* __restrict__ W4,
    const float* __restrict__ b1, const float* __restrict__ b2,
    const float* __restrict__ b3, const float* __restrict__ b4,
    const float* __restrict__ glob, char* __restrict__ ws)
{
  float* biasP = (float*)(ws + BIASPF);
  if (blockIdx.x == 48) {
    int i = threadIdx.x;
    if (i < 128) {
      // layer-1 bias with g@W1[384:512] folded in
      float s = b1[i];
      for (int j = 0; j < 128; ++j) s += glob[j] * W1[(size_t)(384 + j) * D + i];
      biasP[0 * 128 + bias_slot(i)] = s;
    } else {
      int n = i - 128;
      biasP[1 * 128 + bias_slot(n)] = b2[n];
      biasP[2 * 128 + bias_slot(n)] = b3[n];
      biasP[3 * 128 + bias_slot(n)] = b4[n];
    }
    return;
  }
  int tid  = blockIdx.x * 256 + threadIdx.x;
  int lane = tid & 63;
  int f    = tid >> 6;            // 0..191
  const float* W; int base; int lf;
  if (f < 96)       { W = W1; base = L1F; lf = f; }
  else if (f < 128) { W = W2; base = L2F; lf = f - 96; }
  else if (f < 160) { W = W3; base = L3F; lf = f - 128; }
  else              { W = W4; base = L4F; lf = f - 160; }
  int s = lf >> 2, t = lf & 3;
  int k0 = s * 16 + (lane >> 5) * 8;
  int n  = t * 32 + (lane & 31);
  unsigned int pk[4];
#pragma unroll
  for (int p = 0; p < 4; ++p) {
    unsigned int lo = f2bf(W[(size_t)(k0 + 2 * p    ) * D + n]);
    unsigned int hi = f2bf(W[(size_t)(k0 + 2 * p + 1) * D + n]);
    pk[p] = lo | (hi << 16);
  }
  *(uint4*)(ws + base + (size_t)(lf * 64 + lane) * 16) =
      make_uint4(pk[0], pk[1], pk[2], pk[3]);
}

__global__ __launch_bounds__(TPB) void edge_mlp(
    const float* __restrict__ recv, const float* __restrict__ send,
    const float* __restrict__ edge, const char* __restrict__ ws,
    float* __restrict__ out)
{
  // 64KB LDS: buf0 = L2 frags (later re-staged with L4), buf1 = L3 frags
  __shared__ __attribute__((aligned(16))) char smem[65536];
  char* buf0 = smem;
  char* buf1 = smem + 32768;

  const int lane = threadIdx.x & 63;
  const int wid  = threadIdx.x >> 6;   // 0..7
  const int m    = lane & 31;          // edge-row within the wave's 32
  const int hi   = lane >> 5;
  const int row0 = blockIdx.x * ROWS_PER_BLOCK + wid * 32;
  const float* biasF = (const float*)(ws + BIASPF);
  const int lbyte = lane * 16;         // per-lane LDS byte offset within a frag

  // ---- stage L2 -> buf0, L3 -> buf1 (this wave's 4 frags each); read after bar1
#pragma unroll
  for (int i = 0; i < 4; ++i) {
    size_t off = (size_t)(wid * 4 + i) * 1024 + lbyte;
    uint4 v2 = *(const uint4a*)(ws + L2F + off);
    uint4 v3 = *(const uint4a*)(ws + L3F + off);
    *(uint4a*)(buf0 + off) = v2;
    *(uint4a*)(buf1 + off) = v3;
  }

  f32x16 acc[4];
#pragma unroll
  for (int t = 0; t < 4; ++t) acc[t] = (f32x16)0.0f;

  bf16x8 bn[8];   // next-layer B fragments (h, register-resident)

  // epilogue: bias (+relu) on D' = W^T x^T, convert to next layer's B frags
  auto epilogue = [&](int layerOff, bool relu) {
#pragma unroll
    for (int t = 0; t < 4; ++t) {
      const float* bp = biasF + layerOff + t * 32 + hi * 16;
      f32x16 v = acc[t];
#pragma unroll
      for (int q = 0; q < 4; ++q) {
        f32x4 bq = *(const f32x4*)(bp + q * 4);
#pragma unroll
        for (int r = 0; r < 4; ++r) {
          float x = v[q * 4 + r] + bq[r];
          v[q * 4 + r] = relu ? fmaxf(x, 0.0f) : x;
        }
      }
      {
        unsigned int u0 = cvtpk(v[0], v[1]), u1 = cvtpk(v[2], v[3]);
        unsigned int w0 = cvtpk(v[4], v[5]), w1 = cvtpk(v[6], v[7]);
        swap32(u0, w0); swap32(u1, w1);
        union { unsigned int u[4]; bf16x8 b; } pk;
        pk.u[0] = u0; pk.u[1] = u1; pk.u[2] = w0; pk.u[3] = w1;
        bn[2 * t] = pk.b;
      }
      {
        unsigned int u0 = cvtpk(v[8], v[9]),  u1 = cvtpk(v[10], v[11]);
        unsigned int w0 = cvtpk(v[12], v[13]), w1 = cvtpk(v[14], v[15]);
        swap32(u0, w0); swap32(u1, w1);
        union { unsigned int u[4]; bf16x8 b; } pk;
        pk.u[0] = u0; pk.u[1] = u1; pk.u[2] = w0; pk.u[3] = w1;
        bn[2 * t + 1] = pk.b;
      }
      acc[t] = (f32x16)0.0f;
    }
  };

  // -------- layer 1: K = 384 streamed from [recv|send|edge], frags from global (L2$) ----
  const float* rp0 = recv + (size_t)(row0 + m) * D + hi * 8;
  const float* rp1 = send + (size_t)(row0 + m) * D + hi * 8;
  const float* rp2 = edge + (size_t)(row0 + m) * D + hi * 8;
#pragma unroll
  for (int s = 0; s < 24; ++s) {
    const float* p = (s < 8 ? rp0 : s < 16 ? rp1 : rp2) + (s & 7) * 16;
    f32x4 v0 = *(const f32x4*)p;
    f32x4 v1 = *(const f32x4*)(p + 4);
    bf16x8 b = cvt8(v0, v1);
#pragma unroll
    for (int t = 0; t < 4; ++t) {
      bf16x8 a = *(const bf16x8a*)(ws + L1F + (size_t)((s * 4 + t) * 64 + lane) * 16);
      acc[t] = __builtin_amdgcn_mfma_f32_32x32x16_bf16(a, b, acc[t], 0, 0, 0);
    }
  }
  epilogue(0, true);

  // layers 2-4: A-frags from LDS (conflict-free lane*16 + imm-offset ds_read_b128)
  auto do_layer_lds = [&](const char* __restrict__ buf) {
#pragma unroll
    for (int s = 0; s < 8; ++s) {
      bf16x8 b = bn[s];
#pragma unroll
      for (int t = 0; t < 4; ++t) {
        bf16x8 a = *(const bf16x8a*)(buf + (s * 4 + t) * 1024 + lbyte);
        acc[t] = __builtin_amdgcn_mfma_f32_32x32x16_bf16(a, b, acc[t], 0, 0, 0);
      }
    }
  };

  __syncthreads();               // bar1: buf0 (L2) and buf1 (L3) staged & visible
  do_layer_lds(buf0);
  epilogue(128, true);
  __syncthreads();               // bar2: all waves done reading buf0 -> safe to overwrite
#pragma unroll
  for (int i = 0; i < 4; ++i) {  // stage L4 -> buf0 (hides under L3 compute)
    size_t off = (size_t)(wid * 4 + i) * 1024 + lbyte;
    *(uint4a*)(buf0 + off) = *(const uint4a*)(ws + L4F + off);
  }
  do_layer_lds(buf1);
  epilogue(256, true);
  __syncthreads();               // bar3: L4 frags staged & visible
  do_layer_lds(buf0);

  // final: bias, no relu; n = 32t + 8q + 4hi + r is reg-consecutive -> dwordx4 stores
#pragma unroll
  for (int t = 0; t < 4; ++t) {
    const float* bp = biasF + 3 * 128 + t * 32 + hi * 16;
    float* po = out + (size_t)(row0 + m) * D + t * 32 + hi * 4;
#pragma unroll
    for (int q = 0; q < 4; ++q) {
      f32x4 bq = *(const f32x4*)(bp + q * 4);
      f32x4 sv;
#pragma unroll
      for (int r = 0; r < 4; ++r) sv[r] = acc[t][q * 4 + r] + bq[r];
      *(f32x4*)(po + q * 8) = sv;
    }
  }
}

extern "C" void kernel_launch(void* const* d_in, const int* in_sizes, int n_in,
                              void* d_out, int out_size, void* d_ws, size_t ws_size,
                              hipStream_t stream)
{
  const float* recv = (const float*)d_in[0];
  const float* send = (const float*)d_in[1];
  const float* edge = (const float*)d_in[2];
  const float* glob = (const float*)d_in[3];
  const float* W1 = (const float*)d_in[4];
  const float* b1 = (const float*)d_in[5];
  const float* W2 = (const float*)d_in[6];
  const float* b2 = (const float*)d_in[7];
  const float* W3 = (const float*)d_in[8];
  const float* b3 = (const float*)d_in[9];
  const float* W4 = (const float*)d_in[10];
  const float* b4 = (const float*)d_in[11];
  char* ws = (char*)d_ws;

  prep_weights<<<49, 256, 0, stream>>>(W1, W2, W3, W4, b1, b2, b3, b4, glob, ws);
  edge_mlp<<<E_EDGES / ROWS_PER_BLOCK, TPB, 0, stream>>>(recv, send, edge, ws, (float*)d_out);
}